// Round 10
// baseline (280.935 us; speedup 1.0000x reference)
//
#include <hip/hip_runtime.h>
#include <math.h>

// ChamferDistanceL1: B=8, N=M=4096, fp32.
// R16: register-butterfly kernel -- pure-VALU inner loop, cross-lane ONCE.
// R15 post-mortem: __shfl_xor IS the LDS pipe (ds_swizzle/bpermute); its
// "zero-LDS" loop had 24 DS-ops/step + a 6-deep dependent shuffle chain ->
// regressed to 91.8. Lesson (R12/R14/R15): ANY per-step cross-lane op is
// poison. R16 exploits: each x is visited once per lane -> arr[2s]=tree(da)
// is a plain static-index register write. ALL cross-lane work hoisted to a
// single 6-round register butterfly at kernel end (63 shfl/wave TOTAL;
// round k: keep/send via 2 cndmask + shfl_xor(2^k) + min, arr halves each
// round; after round 6 lane l holds block-min for x=l), then one ds_min
// per lane (64 distinct addrs) merges the 8 waves. Inner loop: pure VALU,
// 96 instr/1024 pairs -> floor 10.3us. x via uniform s_load (SGPR).
// Predict fused 13-16us, total 91.8 -> 65-70 (fill ~42 unconditional).

#define BLK 512
#define QPB 64        // x-queries per block
#define NXT 64        // x-tiles per batch
#define YPT 8         // y-points per thread (512*8 = 4096 = all of y)
#define NWAVE 8

#define WSY_DWORDS (8 * NXT * 4096)  // 2,097,152 dwords = 8 MB
#define WSX_DWORDS (8 * NXT * QPB)   // 32,768 dwords = 128 KB

__global__ void zero_out_kernel(float* __restrict__ out) { out[0] = 0.0f; }

// ---- fused kernel (N == M == 4096) ----
__global__ __launch_bounds__(BLK, 4) void chamfer_fused_kernel(
    const float* __restrict__ x, const float* __restrict__ y,
    float* __restrict__ out, unsigned* __restrict__ wsY,
    float* __restrict__ wsX) {
  __shared__ unsigned xmin[QPB];  // block x-mins (uint-ordered floats)

  const int b = blockIdx.y;
  const int xblk = blockIdx.x;
  const float* __restrict__ qb  = x + (size_t)b * 4096 * 3;
  const float* __restrict__ dbb = y + (size_t)b * 4096 * 3;
  const int t = threadIdx.x;
  const int lane = t & 63;

  if (t < QPB) xmin[t] = 0x7F7FFFFFu;
  if (b == 0 && xblk == 0 && t == 0) out[0] = 0.0f;  // reduce runs after us

  // this lane's 8 private y-points (j = r*512 + t), y-min accumulators
  float pyx[YPT], pyy[YPT], pyz[YPT], yacc[YPT];
#pragma unroll
  for (int r = 0; r < YPT; ++r) {
    const int j = r * BLK + t;
    pyx[r] = dbb[3 * j + 0];
    pyy[r] = dbb[3 * j + 1];
    pyz[r] = dbb[3 * j + 2];
    yacc[r] = 3.0e38f;
  }

  // uniform pointer to this block's 64 x-queries (scalarized loads)
  const float* __restrict__ qx0 = qb + (size_t)(xblk * QPB) * 3;

  // per-lane results for all 64 x-queries (write-once, static indices)
  float arr[QPB];

  // ---- fully unrolled: 32 steps x 2 uniform x-queries, PURE VALU ----
#pragma unroll
  for (int s = 0; s < 32; ++s) {
    const float ax = qx0[6 * s + 0], ay = qx0[6 * s + 1], az = qx0[6 * s + 2];
    const float bx = qx0[6 * s + 3], by = qx0[6 * s + 4], bz = qx0[6 * s + 5];
    float da[YPT], db_[YPT];
#pragma unroll
    for (int r = 0; r < YPT; ++r) {
      da[r]  = fabsf(ax - pyx[r]) + fabsf(ay - pyy[r]) + fabsf(az - pyz[r]);
      db_[r] = fabsf(bx - pyx[r]) + fabsf(by - pyy[r]) + fabsf(bz - pyz[r]);
      yacc[r] = fminf(yacc[r], fminf(da[r], db_[r]));  // v_min3_f32
    }
    const float a1 = fminf(fminf(da[0], da[1]), da[2]);
    const float a2 = fminf(fminf(da[3], da[4]), da[5]);
    const float a3 = fminf(fminf(da[6], da[7]), a1);
    arr[2 * s] = fminf(a2, a3);
    const float b1 = fminf(fminf(db_[0], db_[1]), db_[2]);
    const float b2 = fminf(fminf(db_[3], db_[4]), db_[5]);
    const float b3 = fminf(fminf(db_[6], db_[7]), b1);
    arr[2 * s + 1] = fminf(b2, b3);
  }

  // ---- y flush: lane-private partials, coalesced, once ----
  unsigned* __restrict__ wyb = wsY + ((size_t)b * NXT + xblk) * 4096;
#pragma unroll
  for (int r = 0; r < YPT; ++r) {
    wyb[r * BLK + t] = __float_as_uint(yacc[r]);
  }
  __syncthreads();  // xmin init visible before the ds atomics below

  // ---- register butterfly: 6 rounds, arr halves each round ----
  // invariant: after round k, arr[m] = min over the 2^k-lane group of the
  // partial for x-index (m << k) | (lane & (2^k - 1)).
#pragma unroll
  for (int k = 0; k < 6; ++k) {
    const int o = 1 << k;
    const bool hi = (lane & o) != 0;
#pragma unroll
    for (int j = 0; j < (QPB >> (k + 1)); ++j) {
      const float ev = arr[2 * j];      // bit_k(x) = 0
      const float ov = arr[2 * j + 1];  // bit_k(x) = 1
      const float snd = hi ? ev : ov;
      const float kp  = hi ? ov : ev;
      const float rcv = __shfl_xor(snd, o, 64);
      arr[j] = fminf(kp, rcv);
    }
  }
  // arr[0] = this wave's min for x-index == lane; merge 8 waves via LDS
  atomicMin(&xmin[lane], __float_as_uint(arr[0]));
  __syncthreads();

  if (t < QPB) {
    wsX[((size_t)b * NXT + xblk) * QPB + t] = __uint_as_float(xmin[t]);
  }
}

// ---- reduce: y 64-way min (+sy) + x final (+sx) -> 128 atomicAdds ----
__global__ __launch_bounds__(256) void reduce_kernel(
    const unsigned* __restrict__ wsY, const float* __restrict__ wsX,
    float* __restrict__ out, float sx, float sy) {
  const int tid = blockIdx.x * 256 + threadIdx.x;  // [0, 32768)
  const int b = tid >> 12;
  const int j = tid & 4095;

  // y-side: min over the 64 x-blocks' partials for y-point (b, j)
  const unsigned* __restrict__ py = wsY + ((size_t)b * NXT) * 4096 + j;
  unsigned um = 0x7F7FFFFFu;
#pragma unroll 8
  for (int xb = 0; xb < NXT; ++xb) um = min(um, py[(size_t)xb * 4096]);

  // x-side: entry tid is already the final x-min for query (b, i=j)
  float s = __uint_as_float(um) * sy + wsX[tid] * sx;
#pragma unroll
  for (int o = 32; o > 0; o >>= 1) s += __shfl_down(s, o, 64);
  __shared__ float ws[4];
  const int w = threadIdx.x >> 6;
  if ((threadIdx.x & 63) == 0) ws[w] = s;
  __syncthreads();
  if (threadIdx.x == 0) atomicAdd(out, ws[0] + ws[1] + ws[2] + ws[3]);
}

// ---------------- generic fallback (any N, M): R8 two-dir kernel ----------
#define GBLK 512
#define GQPB 64
#define GQPT 4
#define GSLICE 1024
#define GNGRP 32
#define GGRANGE (GSLICE / GNGRP)

__global__ __launch_bounds__(GBLK) void chamfer_generic_kernel(
    const float* __restrict__ x, const float* __restrict__ y,
    float* __restrict__ out, int N, int M, float sx, float sy) {
  __shared__ float4 sdb[GNGRP][GGRANGE + 1];
  __shared__ float pmin[GBLK / 64][GQPB];
  const int dir = blockIdx.z;
  const int b = blockIdx.y;
  const float* __restrict__ q  = dir ? y : x;
  const float* __restrict__ db = dir ? x : y;
  const int Nq  = dir ? M : N;
  const int Ndb = dir ? N : M;
  const float scale = dir ? sy : sx;
  const float* __restrict__ qb  = q  + (size_t)b * Nq  * 3;
  const float* __restrict__ dbb = db + (size_t)b * Ndb * 3;
  const int t = threadIdx.x;
  const int g = t >> 4, u = t & 15;
  const int q0 = blockIdx.x * GQPB;
  float qx[GQPT], qy[GQPT], qz[GQPT], dmin[GQPT];
#pragma unroll
  for (int k = 0; k < GQPT; ++k) {
    int qi = q0 + u + 16 * k;
    if (qi >= Nq) qi = Nq - 1;
    qx[k] = qb[3 * qi + 0];
    qy[k] = qb[3 * qi + 1];
    qz[k] = qb[3 * qi + 2];
    dmin[k] = 3.0e38f;
  }
  for (int s0 = 0; s0 < Ndb; s0 += GSLICE) {
    const int send = min(GSLICE, Ndb - s0);
    for (int p = t; p < send; p += GBLK) {
      const int j = s0 + p;
      sdb[p >> 5][p & 31] =
          make_float4(dbb[3 * j + 0], dbb[3 * j + 1], dbb[3 * j + 2], 0.0f);
    }
    __syncthreads();
    const int base = g * GGRANGE;
    const int lim = min(GGRANGE, max(0, send - base));
    for (int tt = 0; tt < lim; ++tt) {
      const float4 p0 = sdb[g][tt];
#pragma unroll
      for (int k = 0; k < GQPT; ++k) {
        const float d0 =
            fabsf(qx[k] - p0.x) + fabsf(qy[k] - p0.y) + fabsf(qz[k] - p0.z);
        dmin[k] = fminf(dmin[k], d0);
      }
    }
    __syncthreads();
  }
#pragma unroll
  for (int k = 0; k < GQPT; ++k) {
    float m = dmin[k];
    m = fminf(m, __shfl_xor(m, 16, 64));
    m = fminf(m, __shfl_xor(m, 32, 64));
    dmin[k] = m;
  }
  const int w = t >> 6, l = t & 63;
  if (l < 16) {
#pragma unroll
    for (int k = 0; k < GQPT; ++k) pmin[w][l + 16 * k] = dmin[k];
  }
  __syncthreads();
  if (t < GQPB) {
    float m = pmin[0][t];
#pragma unroll
    for (int ww = 1; ww < GBLK / 64; ++ww) m = fminf(m, pmin[ww][t]);
    if (q0 + t >= Nq) m = 0.0f;
#pragma unroll
    for (int o = 32; o > 0; o >>= 1) m += __shfl_down(m, o, 64);
    if (t == 0) atomicAdd(out, m * scale);
  }
}

extern "C" void kernel_launch(void* const* d_in, const int* in_sizes, int n_in,
                              void* d_out, int out_size, void* d_ws, size_t ws_size,
                              hipStream_t stream) {
  const float* x = (const float*)d_in[0];
  const float* y = (const float*)d_in[1];
  const int B = 8;
  const int N = in_sizes[0] / (B * 3);
  const int M = in_sizes[1] / (B * 3);

  float* out = (float*)d_out;
  unsigned* wsY = (unsigned*)d_ws;                 // 8 MB
  float* wsX = (float*)d_ws + WSY_DWORDS;          // + 128 KB
  const float sx = 1.0f / (float)(B * N);
  const float sy = 1.0f / (float)(B * M);

  const bool fused =
      (N == 4096 && M == 4096 &&
       ws_size >= (size_t)(WSY_DWORDS + WSX_DWORDS) * 4);
  if (fused) {
    dim3 grd(NXT, B);  // 64 x-tiles * 8 batches = 512 blocks
    chamfer_fused_kernel<<<grd, dim3(BLK), 0, stream>>>(x, y, out, wsY, wsX);
    reduce_kernel<<<(8 * 4096) / 256, 256, 0, stream>>>(wsY, wsX, out, sx, sy);
  } else {
    zero_out_kernel<<<1, 1, 0, stream>>>(out);
    const int mx = (N > M) ? N : M;
    dim3 grd((mx + GQPB - 1) / GQPB, B, 2);
    chamfer_generic_kernel<<<grd, dim3(GBLK), 0, stream>>>(
        x, y, out, N, M, sx, sy);
  }
}

// Round 11
// 83.933 us; speedup vs baseline: 3.3471x; 3.3471x over previous
//
#include <hip/hip_runtime.h>
#include <math.h>

// ChamferDistanceL1: B=8, N=M=4096, fp32.
// R17: chunked register butterfly. R16 post-mortem: arr[64] + 32 y-regs
// spilled to scratch (VGPR_Count=64 cliff, FETCH 208MB / WRITE 420MB of
// scratch traffic, 225us). The butterfly idea was never actually tested.
// R17 processes x in CHUNKS OF 8: arr[8] (static idx, fits regs), 6-round
// butterfly per chunk (rounds 0-2 shrink arr 8->1, rounds 3-5 merge lanes
// sharing lane&7; 10 shfl + ~34 ALU per chunk), then ONE 8-lane predicated
// ds_min with distinct addresses merges waves. 80 shfl + 8 LDS atomics per
// wave per KERNEL (~3% of slots). Inner loop stays pure VALU (96 instrs /
// 1024 pairs). VGPR ~80 < 128 cap -> no spill. Predict fused 14-20us (out
// of top-5, WRITE ~8.6MB), total 280.9 -> 68-75 (fill ~42 unconditional).

#define BLK 512
#define QPB 64        // x-queries per block
#define NXT 64        // x-tiles per batch
#define YPT 8         // y-points per thread (512*8 = 4096 = all of y)
#define NWAVE 8

#define WSY_DWORDS (8 * NXT * 4096)  // 2,097,152 dwords = 8 MB
#define WSX_DWORDS (8 * NXT * QPB)   // 32,768 dwords = 128 KB

__global__ void zero_out_kernel(float* __restrict__ out) { out[0] = 0.0f; }

// ---- fused kernel (N == M == 4096) ----
__global__ __launch_bounds__(BLK, 4) void chamfer_fused_kernel(
    const float* __restrict__ x, const float* __restrict__ y,
    float* __restrict__ out, unsigned* __restrict__ wsY,
    float* __restrict__ wsX) {
  __shared__ unsigned xmin[QPB];  // block x-mins (uint-ordered floats)

  const int b = blockIdx.y;
  const int xblk = blockIdx.x;
  const float* __restrict__ qb  = x + (size_t)b * 4096 * 3;
  const float* __restrict__ dbb = y + (size_t)b * 4096 * 3;
  const int t = threadIdx.x;
  const int lane = t & 63;

  if (t < QPB) xmin[t] = 0x7F7FFFFFu;
  if (b == 0 && xblk == 0 && t == 0) out[0] = 0.0f;  // reduce runs after us

  // this lane's 8 private y-points (j = r*512 + t), y-min accumulators
  float pyx[YPT], pyy[YPT], pyz[YPT], yacc[YPT];
#pragma unroll
  for (int r = 0; r < YPT; ++r) {
    const int j = r * BLK + t;
    pyx[r] = dbb[3 * j + 0];
    pyy[r] = dbb[3 * j + 1];
    pyz[r] = dbb[3 * j + 2];
    yacc[r] = 3.0e38f;
  }

  // uniform pointer to this block's 64 x-queries (scalarized loads)
  const float* __restrict__ qx0 = qb + (size_t)(xblk * QPB) * 3;

  __syncthreads();  // xmin init visible before the per-chunk ds_min below

  // ---- 8 chunks x 8 x-queries; inner loop pure VALU ----
  for (int c = 0; c < 8; ++c) {
    const float* __restrict__ qc = qx0 + 24 * c;
    float arr[8];  // per-lane results for this chunk (write-once, static)
#pragma unroll
    for (int s = 0; s < 4; ++s) {
      const float ax = qc[6 * s + 0], ay = qc[6 * s + 1], az = qc[6 * s + 2];
      const float bx = qc[6 * s + 3], by = qc[6 * s + 4], bz = qc[6 * s + 5];
      float da[YPT], db_[YPT];
#pragma unroll
      for (int r = 0; r < YPT; ++r) {
        da[r]  = fabsf(ax - pyx[r]) + fabsf(ay - pyy[r]) + fabsf(az - pyz[r]);
        db_[r] = fabsf(bx - pyx[r]) + fabsf(by - pyy[r]) + fabsf(bz - pyz[r]);
        yacc[r] = fminf(yacc[r], fminf(da[r], db_[r]));  // v_min3_f32
      }
      const float a1 = fminf(fminf(da[0], da[1]), da[2]);
      const float a2 = fminf(fminf(da[3], da[4]), da[5]);
      const float a3 = fminf(fminf(da[6], da[7]), a1);
      arr[2 * s] = fminf(a2, a3);
      const float b1 = fminf(fminf(db_[0], db_[1]), db_[2]);
      const float b2 = fminf(fminf(db_[3], db_[4]), db_[5]);
      const float b3 = fminf(fminf(db_[6], db_[7]), b1);
      arr[2 * s + 1] = fminf(b2, b3);
    }
    // butterfly rounds 0-2: arr halves each round.
    // invariant after round k: arr[m] = min over the 2^(k+1)-lane... i.e.
    // arr[m] holds x-offset (m<<(k+1))|(lane&(2^(k+1)-1)) min over the
    // lane's 2^(k+1)-group.
#pragma unroll
    for (int k = 0; k < 3; ++k) {
      const int o = 1 << k;
      const bool hi = (lane & o) != 0;
#pragma unroll
      for (int j = 0; j < (8 >> (k + 1)); ++j) {
        const float ev = arr[2 * j];      // x-offset bit_k = 0
        const float ov = arr[2 * j + 1];  // x-offset bit_k = 1
        const float snd = hi ? ev : ov;
        const float kp  = hi ? ov : ev;
        arr[j] = fminf(kp, __shfl_xor(snd, o, 64));
      }
    }
    // rounds 3-5: lanes sharing (lane&7) hold the same x-offset
    float m = arr[0];
    m = fminf(m, __shfl_xor(m, 8, 64));
    m = fminf(m, __shfl_xor(m, 16, 64));
    m = fminf(m, __shfl_xor(m, 32, 64));
    // 8 distinct addresses within the one atomic instruction; 8 waves merge
    if (lane < 8) atomicMin(&xmin[c * 8 + lane], __float_as_uint(m));
  }

  // ---- y flush: lane-private partials, coalesced, once ----
  unsigned* __restrict__ wyb = wsY + ((size_t)b * NXT + xblk) * 4096;
#pragma unroll
  for (int r = 0; r < YPT; ++r) {
    wyb[r * BLK + t] = __float_as_uint(yacc[r]);
  }
  __syncthreads();  // all waves' ds_min done

  if (t < QPB) {
    wsX[((size_t)b * NXT + xblk) * QPB + t] = __uint_as_float(xmin[t]);
  }
}

// ---- reduce: y 64-way min (+sy) + x final (+sx) -> 128 atomicAdds ----
__global__ __launch_bounds__(256) void reduce_kernel(
    const unsigned* __restrict__ wsY, const float* __restrict__ wsX,
    float* __restrict__ out, float sx, float sy) {
  const int tid = blockIdx.x * 256 + threadIdx.x;  // [0, 32768)
  const int b = tid >> 12;
  const int j = tid & 4095;

  // y-side: min over the 64 x-blocks' partials for y-point (b, j)
  const unsigned* __restrict__ py = wsY + ((size_t)b * NXT) * 4096 + j;
  unsigned um = 0x7F7FFFFFu;
#pragma unroll 8
  for (int xb = 0; xb < NXT; ++xb) um = min(um, py[(size_t)xb * 4096]);

  // x-side: entry tid is already the final x-min for query (b, i=j)
  float s = __uint_as_float(um) * sy + wsX[tid] * sx;
#pragma unroll
  for (int o = 32; o > 0; o >>= 1) s += __shfl_down(s, o, 64);
  __shared__ float ws[4];
  const int w = threadIdx.x >> 6;
  if ((threadIdx.x & 63) == 0) ws[w] = s;
  __syncthreads();
  if (threadIdx.x == 0) atomicAdd(out, ws[0] + ws[1] + ws[2] + ws[3]);
}

// ---------------- generic fallback (any N, M): R8 two-dir kernel ----------
#define GBLK 512
#define GQPB 64
#define GQPT 4
#define GSLICE 1024
#define GNGRP 32
#define GGRANGE (GSLICE / GNGRP)

__global__ __launch_bounds__(GBLK) void chamfer_generic_kernel(
    const float* __restrict__ x, const float* __restrict__ y,
    float* __restrict__ out, int N, int M, float sx, float sy) {
  __shared__ float4 sdb[GNGRP][GGRANGE + 1];
  __shared__ float pmin[GBLK / 64][GQPB];
  const int dir = blockIdx.z;
  const int b = blockIdx.y;
  const float* __restrict__ q  = dir ? y : x;
  const float* __restrict__ db = dir ? x : y;
  const int Nq  = dir ? M : N;
  const int Ndb = dir ? N : M;
  const float scale = dir ? sy : sx;
  const float* __restrict__ qb  = q  + (size_t)b * Nq  * 3;
  const float* __restrict__ dbb = db + (size_t)b * Ndb * 3;
  const int t = threadIdx.x;
  const int g = t >> 4, u = t & 15;
  const int q0 = blockIdx.x * GQPB;
  float qx[GQPT], qy[GQPT], qz[GQPT], dmin[GQPT];
#pragma unroll
  for (int k = 0; k < GQPT; ++k) {
    int qi = q0 + u + 16 * k;
    if (qi >= Nq) qi = Nq - 1;
    qx[k] = qb[3 * qi + 0];
    qy[k] = qb[3 * qi + 1];
    qz[k] = qb[3 * qi + 2];
    dmin[k] = 3.0e38f;
  }
  for (int s0 = 0; s0 < Ndb; s0 += GSLICE) {
    const int send = min(GSLICE, Ndb - s0);
    for (int p = t; p < send; p += GBLK) {
      const int j = s0 + p;
      sdb[p >> 5][p & 31] =
          make_float4(dbb[3 * j + 0], dbb[3 * j + 1], dbb[3 * j + 2], 0.0f);
    }
    __syncthreads();
    const int base = g * GGRANGE;
    const int lim = min(GGRANGE, max(0, send - base));
    for (int tt = 0; tt < lim; ++tt) {
      const float4 p0 = sdb[g][tt];
#pragma unroll
      for (int k = 0; k < GQPT; ++k) {
        const float d0 =
            fabsf(qx[k] - p0.x) + fabsf(qy[k] - p0.y) + fabsf(qz[k] - p0.z);
        dmin[k] = fminf(dmin[k], d0);
      }
    }
    __syncthreads();
  }
#pragma unroll
  for (int k = 0; k < GQPT; ++k) {
    float m = dmin[k];
    m = fminf(m, __shfl_xor(m, 16, 64));
    m = fminf(m, __shfl_xor(m, 32, 64));
    dmin[k] = m;
  }
  const int w = t >> 6, l = t & 63;
  if (l < 16) {
#pragma unroll
    for (int k = 0; k < GQPT; ++k) pmin[w][l + 16 * k] = dmin[k];
  }
  __syncthreads();
  if (t < GQPB) {
    float m = pmin[0][t];
#pragma unroll
    for (int ww = 1; ww < GBLK / 64; ++ww) m = fminf(m, pmin[ww][t]);
    if (q0 + t >= Nq) m = 0.0f;
#pragma unroll
    for (int o = 32; o > 0; o >>= 1) m += __shfl_down(m, o, 64);
    if (t == 0) atomicAdd(out, m * scale);
  }
}

extern "C" void kernel_launch(void* const* d_in, const int* in_sizes, int n_in,
                              void* d_out, int out_size, void* d_ws, size_t ws_size,
                              hipStream_t stream) {
  const float* x = (const float*)d_in[0];
  const float* y = (const float*)d_in[1];
  const int B = 8;
  const int N = in_sizes[0] / (B * 3);
  const int M = in_sizes[1] / (B * 3);

  float* out = (float*)d_out;
  unsigned* wsY = (unsigned*)d_ws;                 // 8 MB
  float* wsX = (float*)d_ws + WSY_DWORDS;          // + 128 KB
  const float sx = 1.0f / (float)(B * N);
  const float sy = 1.0f / (float)(B * M);

  const bool fused =
      (N == 4096 && M == 4096 &&
       ws_size >= (size_t)(WSY_DWORDS + WSX_DWORDS) * 4);
  if (fused) {
    dim3 grd(NXT, B);  // 64 x-tiles * 8 batches = 512 blocks
    chamfer_fused_kernel<<<grd, dim3(BLK), 0, stream>>>(x, y, out, wsY, wsX);
    reduce_kernel<<<(8 * 4096) / 256, 256, 0, stream>>>(wsY, wsX, out, sx, sy);
  } else {
    zero_out_kernel<<<1, 1, 0, stream>>>(out);
    const int mx = (N > M) ? N : M;
    dim3 grd((mx + GQPB - 1) / GQPB, B, 2);
    chamfer_generic_kernel<<<grd, dim3(GBLK), 0, stream>>>(
        x, y, out, N, M, sx, sy);
  }
}